// Round 8
// baseline (132.449 us; speedup 1.0000x reference)
//
#include <hip/hip_runtime.h>
#include <stdint.h>

typedef unsigned short u16;
typedef __attribute__((ext_vector_type(8))) short short8;
typedef __attribute__((ext_vector_type(4))) short short4v;
typedef __attribute__((ext_vector_type(4))) float f32x4;

#define NB    16
#define DIM   256
#define NTOK  1024

__device__ __forceinline__ u16 f2b(float f) {
    union { float f; uint32_t u; } v; v.f = f;
    uint32_t u = v.u;
    u += 0x7fffu + ((u >> 16) & 1u);
    return (u16)(u >> 16);
}
__device__ __forceinline__ uint32_t pack2(float a, float b) {
    return (uint32_t)f2b(a) | ((uint32_t)f2b(b) << 16);
}
__device__ __forceinline__ f32x4 mfma16(short8 a, short8 b, f32x4 c) {
    return __builtin_amdgcn_mfma_f32_16x16x32_bf16(a, b, c, 0, 0, 0);
}
// K=16 MFMA via inline asm (D,C tied). B-frag k=4*hi+j matches in-lane P layout.
__device__ __forceinline__ f32x4 mfma16k16(short4v a, short4v b, f32x4 c) {
    asm volatile("v_mfma_f32_16x16x16_bf16 %0, %1, %2, %0"
                 : "+v"(c) : "v"(a), "v"(b));
    return c;
}
__device__ __forceinline__ short8 ld8(const u16* p) {
    return *reinterpret_cast<const short8*>(p);
}
__device__ __forceinline__ short4v ld4(const u16* p) {
    return *reinterpret_cast<const short4v*>(p);
}
__device__ __forceinline__ void gl_lds(const u16* g, u16* l) {
    __builtin_amdgcn_global_load_lds((const __attribute__((address_space(1))) void*)g,
                                     (__attribute__((address_space(3))) void*)l, 16, 0, 0);
}

// ---------------- Kernel 1: pack x -> xbf (bf16, [C][N]) + nodes (bf16 transpose, [N][C])
__global__ __launch_bounds__(256) void pack_kernel(const float* __restrict__ x,
                                                   u16* __restrict__ xbf,
                                                   u16* __restrict__ nodes) {
    __shared__ float tile[64][67];
    int tid = threadIdx.x;
    int blk = blockIdx.x;          // 1024 blocks
    int b  = blk >> 6;
    int t  = blk & 63;
    int c0 = (t >> 4) << 6;
    int n0 = (t & 15) << 6;
    const float* xb = x + (size_t)b * (DIM * NTOK);
    u16* xbb = xbf + (size_t)b * (DIM * NTOK);
#pragma unroll
    for (int i = 0; i < 4; i++) {
        int idx = i * 256 + tid;
        int cl = idx >> 4, nq = idx & 15;
        float4 f = *reinterpret_cast<const float4*>(xb + (size_t)(c0 + cl) * NTOK + n0 + nq * 4);
        tile[cl][nq * 4 + 0] = f.x;
        tile[cl][nq * 4 + 1] = f.y;
        tile[cl][nq * 4 + 2] = f.z;
        tile[cl][nq * 4 + 3] = f.w;
        ushort4 s;
        s.x = f2b(f.x); s.y = f2b(f.y); s.z = f2b(f.z); s.w = f2b(f.w);
        *reinterpret_cast<ushort4*>(xbb + (size_t)(c0 + cl) * NTOK + n0 + nq * 4) = s;
    }
    __syncthreads();
#pragma unroll
    for (int i = 0; i < 4; i++) {
        int idx = i * 256 + tid;
        int nl = idx >> 4, cq = idx & 15;
        ushort4 s;
        s.x = f2b(tile[cq * 4 + 0][nl]);
        s.y = f2b(tile[cq * 4 + 1][nl]);
        s.z = f2b(tile[cq * 4 + 2][nl]);
        s.w = f2b(tile[cq * 4 + 3][nl]);
        *reinterpret_cast<ushort4*>(nodes + (size_t)(b * NTOK + n0 + nl) * DIM + c0 + cq * 4) = s;
    }
}

// ---------------- Kernel 2: convert 3 weight matrices to bf16
__global__ __launch_bounds__(256) void wconv_kernel(const float* __restrict__ a,
                                                    const float* __restrict__ b,
                                                    const float* __restrict__ c,
                                                    u16* __restrict__ o) {
    int i = blockIdx.x * 256 + threadIdx.x;
    const float* s = (i < 65536) ? a : (i < 131072) ? b : c;
    o[i] = f2b(s[i & 65535]);
}

// ---------------- Kernel 3: q = nodes @ proj_w^T + proj_b
__global__ __launch_bounds__(256) void proj_kernel(const u16* __restrict__ nodes,
                                                   const u16* __restrict__ wbf,
                                                   const float* __restrict__ pb,
                                                   u16* __restrict__ qb) {
    int lane = threadIdx.x & 63;
    int w = threadIdx.x >> 6;
    int lo = lane & 15, hi = lane >> 4;
    int ch = blockIdx.x & 1;
    int row0 = (blockIdx.x >> 1) * 64 + w * 16;
    const u16* arow = nodes + (size_t)(row0 + lo) * DIM + hi * 8;
    f32x4 acc[8];
#pragma unroll
    for (int i = 0; i < 8; i++) acc[i] = (f32x4){0.f, 0.f, 0.f, 0.f};
#pragma unroll
    for (int t = 0; t < 8; t++) {
        short8 a = ld8(arow + t * 32);
#pragma unroll
        for (int nf = 0; nf < 8; nf++) {
            short8 bfr = ld8(wbf + ((ch * 8 + nf) * 16 + lo) * DIM + t * 32 + hi * 8);
            acc[nf] = mfma16(a, bfr, acc[nf]);
        }
    }
#pragma unroll
    for (int nf = 0; nf < 8; nf++) {
        int col = (ch * 8 + nf) * 16 + lo;
        float bias = pb[col];
#pragma unroll
        for (int r = 0; r < 4; r++) {
            int row = row0 + hi * 4 + r;
            qb[(size_t)row * DIM + col] = f2b(acc[nf][r] + bias);
        }
    }
}

// ---------------- Kernel 4: flash attention, 8 waves = 4 q-tiles x 2 ch-halves.
// 256 blocks (16 qb x 16 batches), 512 threads -> 8 waves/CU = 2/SIMD.
// Wave pair duplicates QK+softmax for its q-tile; each wave does PV for half
// the channels via two K=16 MFMA steps (B-frag is in-lane -> NO shuffles).
__global__ __launch_bounds__(512) void attn_kernel(const u16* __restrict__ qb,
                                                   const u16* __restrict__ xbf,
                                                   u16* __restrict__ agg) {
    __shared__ u16 kls[2][32 * 256];   // 2 x 16 KB  [kvrow][256ch], swz slot^=row&7
    __shared__ u16 vls[2][256 * 32];   // 2 x 16 KB  [ch][32kv],    swz slot^=ch&3

    int lane = threadIdx.x & 63;
    int w = threadIdx.x >> 6;            // 0..7
    int qsel = w >> 1, wch = w & 1;
    int lo = lane & 15, hi = lane >> 4;
    int b  = blockIdx.x & 15;            // batch-per-XCD mapping
    int qt = blockIdx.x >> 4;            // 0..15
    int q0 = qt * 64 + qsel * 16;
    const u16* qbb = qb  + (size_t)b * (NTOK * DIM);
    const u16* xbb = xbf + (size_t)b * (DIM * NTOK);

    // staging assignments: per wave 2 K-instr (4 rows) + 2 V-instr (32 ch)
    int kOff[2], vOff[2], kDst[2], vDst[2];
#pragma unroll
    for (int i = 0; i < 2; i++) {
        int kr = w * 4 + i * 2 + (lane >> 5);
        kOff[i] = kr * DIM + ((lane & 31) ^ (kr & 7)) * 8;
        kDst[i] = (w * 4 + i * 2) * 256;
        int vc = w * 32 + i * 16 + (lane >> 2);
        vOff[i] = vc * NTOK + ((lane & 3) ^ (vc & 3)) * 8;
        vDst[i] = (w * 32 + i * 16) * 32;
    }

    short8 bq[8];
#pragma unroll
    for (int t = 0; t < 8; t++)
        bq[t] = ld8(qbb + (size_t)(q0 + lo) * DIM + t * 32 + hi * 8);

    f32x4 acc[8];
#pragma unroll
    for (int i = 0; i < 8; i++) acc[i] = (f32x4){0.f, 0.f, 0.f, 0.f};
    float m = -1e30f, ell = 0.f;
    const float C1 = 0.0625f * 1.44269504f;
    const float THR = 11.5f;

    // prologue: stage tile 0 into buf 0
#pragma unroll
    for (int i = 0; i < 2; i++) {
        gl_lds(qbb + kOff[i], &kls[0][kDst[i]]);
        gl_lds(xbb + vOff[i], &vls[0][vDst[i]]);
    }
    __syncthreads();

    // per-lane PV read invariants
    int vbase = lo * 32 + (hi & 1) * 4;   // elements
    int vkey = lo & 3;
    int hh = hi >> 1;

    for (int tt = 0; tt < 32; tt++) {
        int buf = tt & 1;
        if (tt < 31) {
            int base = (tt + 1) * 32;
#pragma unroll
            for (int i = 0; i < 2; i++) {
                gl_lds(qbb + base * DIM + kOff[i], &kls[buf ^ 1][kDst[i]]);
                gl_lds(xbb + base       + vOff[i], &vls[buf ^ 1][vDst[i]]);
            }
        }
        const u16* kb = &kls[buf][0];
        const u16* vb = &vls[buf][0];

        // QK^T: 2 score frags (kv 0..15, 16..31), split chains
        f32x4 s0a = (f32x4){0.f,0.f,0.f,0.f}, s0b = (f32x4){0.f,0.f,0.f,0.f};
        f32x4 s1a = (f32x4){0.f,0.f,0.f,0.f}, s1b = (f32x4){0.f,0.f,0.f,0.f};
        __builtin_amdgcn_s_setprio(1);
#pragma unroll
        for (int t = 0; t < 8; t += 2) {
            int sl0 = ((t * 4 + hi) ^ (lo & 7)) * 8;
            int sl1 = (((t + 1) * 4 + hi) ^ (lo & 7)) * 8;
            s0a = mfma16(ld8(kb + lo * 256 + sl0),        bq[t],     s0a);
            s0b = mfma16(ld8(kb + lo * 256 + sl1),        bq[t + 1], s0b);
            s1a = mfma16(ld8(kb + (16 + lo) * 256 + sl0), bq[t],     s1a);
            s1b = mfma16(ld8(kb + (16 + lo) * 256 + sl1), bq[t + 1], s1b);
        }
        __builtin_amdgcn_s_setprio(0);

        float p0[4], p1[4];
        float pm = -1e30f;
#pragma unroll
        for (int r = 0; r < 4; r++) {
            p0[r] = (s0a[r] + s0b[r]) * C1;
            p1[r] = (s1a[r] + s1b[r]) * C1;
            pm = fmaxf(pm, fmaxf(p0[r], p1[r]));
        }
        pm = fmaxf(pm, __shfl_xor(pm, 16));
        pm = fmaxf(pm, __shfl_xor(pm, 32));
        if (!__all(pm <= m + THR)) {
            float mnew = fmaxf(m, pm);
            float sc = exp2f(m - mnew);
            ell *= sc;
#pragma unroll
            for (int i = 0; i < 8; i++) {
                acc[i][0] *= sc; acc[i][1] *= sc; acc[i][2] *= sc; acc[i][3] *= sc;
            }
            m = mnew;
        }
        float psum = 0.f;
#pragma unroll
        for (int r = 0; r < 4; r++) {
            p0[r] = exp2f(p0[r] - m);
            p1[r] = exp2f(p1[r] - m);
            psum += p0[r] + p1[r];
        }
        psum += __shfl_xor(psum, 16);
        psum += __shfl_xor(psum, 32);
        ell += psum;

        // B-frags for K=16 PV: in-lane (k = 4*hi+j), no shuffles
        union { uint32_t u[2]; short4v v; } pa, pb2;
        pa.u[0]  = pack2(p0[0], p0[1]); pa.u[1]  = pack2(p0[2], p0[3]);
        pb2.u[0] = pack2(p1[0], p1[1]); pb2.u[1] = pack2(p1[2], p1[3]);

        // PV: 8 ch-frags (this wave's half), 2 K=16 steps
        __builtin_amdgcn_s_setprio(1);
#pragma unroll
        for (int mf = 0; mf < 8; mf++) {
            const u16* vrow = vb + ((wch * 8 + mf) * 16) * 32 + vbase;
            short4v v0 = ld4(vrow + ((0 + hh) ^ vkey) * 8);
            short4v v1 = ld4(vrow + ((2 + hh) ^ vkey) * 8);
            acc[mf] = mfma16k16(v0, pa.v,  acc[mf]);
            acc[mf] = mfma16k16(v1, pb2.v, acc[mf]);
        }
        __builtin_amdgcn_s_setprio(0);
        __syncthreads();
    }

    asm volatile("s_nop 7\n\ts_nop 7" ::: "memory");  // asm-MFMA -> VALU hazard guard
    float rinv = 1.f / ell;
#pragma unroll
    for (int mf = 0; mf < 8; mf++) {
        ushort4 st;
        st.x = f2b(acc[mf][0] * rinv);
        st.y = f2b(acc[mf][1] * rinv);
        st.z = f2b(acc[mf][2] * rinv);
        st.w = f2b(acc[mf][3] * rinv);
        *reinterpret_cast<ushort4*>(agg + (size_t)(b * NTOK + q0 + lo) * DIM +
                                    (wch * 8 + mf) * 16 + hi * 4) = st;
    }
}

// ---------------- Kernel 5: FFN + residual, 8-wave blocks (4 rowtiles x 2 colhalves).
__global__ __launch_bounds__(512) void ffn_kernel(const u16* __restrict__ agg,
                                                  const u16* __restrict__ wbf,
                                                  const float* __restrict__ b1,
                                                  const float* __restrict__ b2,
                                                  const float* __restrict__ x,
                                                  float* __restrict__ out) {
    __shared__ u16 hl[64][264];
    int lane = threadIdx.x & 63;
    int w = threadIdx.x >> 6;
    int wr = w & 3, wc = w >> 2;
    int lo = lane & 15, hi = lane >> 4;
    int row0 = blockIdx.x * 64;
    int rw = row0 + wr * 16;
    const u16* w1b = wbf + 65536;
    const u16* w2b = wbf + 131072;

    f32x4 acc[8];
#pragma unroll
    for (int i = 0; i < 8; i++) acc[i] = (f32x4){0.f, 0.f, 0.f, 0.f};
    const u16* arow = agg + (size_t)(rw + lo) * DIM + hi * 8;
#pragma unroll
    for (int t = 0; t < 8; t++) {
        short8 a = ld8(arow + t * 32);
#pragma unroll
        for (int nf = 0; nf < 8; nf++) {
            short8 bfr = ld8(w1b + ((wc * 8 + nf) * 16 + lo) * DIM + t * 32 + hi * 8);
            acc[nf] = mfma16(a, bfr, acc[nf]);
        }
    }
#pragma unroll
    for (int nf = 0; nf < 8; nf++) {
        int f = (wc * 8 + nf) * 16 + lo;
        float bias = b1[f];
#pragma unroll
        for (int r = 0; r < 4; r++) {
            float v = acc[nf][r] + bias;
            float g = 0.5f * v * (1.f + erff(v * 0.70710678f));
            hl[wr * 16 + hi * 4 + r][f] = f2b(g);
        }
    }
    __syncthreads();

    f32x4 acc2[8];
#pragma unroll
    for (int i = 0; i < 8; i++) acc2[i] = (f32x4){0.f, 0.f, 0.f, 0.f};
#pragma unroll
    for (int t = 0; t < 8; t++) {
        short8 bh = ld8(&hl[wr * 16 + lo][t * 32 + hi * 8]);
#pragma unroll
        for (int mf = 0; mf < 8; mf++) {
            short8 a = ld8(w2b + ((wc * 8 + mf) * 16 + lo) * DIM + t * 32 + hi * 8);
            acc2[mf] = mfma16(a, bh, acc2[mf]);
        }
    }
    int bidx = row0 >> 10;
    int n = (rw & 1023) + lo;
#pragma unroll
    for (int mf = 0; mf < 8; mf++) {
#pragma unroll
        for (int r = 0; r < 4; r++) {
            int co = (wc * 8 + mf) * 16 + hi * 4 + r;
            size_t addr = (size_t)bidx * (DIM * NTOK) + (size_t)co * NTOK + n;
            out[addr] = acc2[mf][r] + b2[co] + x[addr];
        }
    }
}

extern "C" void kernel_launch(void* const* d_in, const int* in_sizes, int n_in,
                              void* d_out, int out_size, void* d_ws, size_t ws_size,
                              hipStream_t stream) {
    const float* x      = (const float*)d_in[0];
    const float* proj_w = (const float*)d_in[1];
    const float* proj_b = (const float*)d_in[2];
    const float* w1     = (const float*)d_in[3];
    const float* b1     = (const float*)d_in[4];
    const float* w2     = (const float*)d_in[5];
    const float* b2     = (const float*)d_in[6];
    float* out = (float*)d_out;

    u16* xbf   = (u16*)d_ws;
    u16* nodes = xbf   + 4194304;
    u16* qb    = nodes + 4194304;
    u16* agg   = qb    + 4194304;
    u16* wbf   = agg   + 4194304;

    pack_kernel <<<1024, 256, 0, stream>>>(x, xbf, nodes);
    wconv_kernel<<<768,  256, 0, stream>>>(proj_w, w1, w2, wbf);
    proj_kernel <<<512,  256, 0, stream>>>(nodes, wbf, proj_b, qb);
    attn_kernel <<<256,  512, 0, stream>>>(qb, xbf, agg);
    ffn_kernel  <<<256,  512, 0, stream>>>(agg, wbf, b1, b2, x, out);
}

// Round 9
// 116.221 us; speedup vs baseline: 1.1396x; 1.1396x over previous
//
#include <hip/hip_runtime.h>
#include <stdint.h>

typedef unsigned short u16;
typedef __attribute__((ext_vector_type(8))) short short8;
typedef __attribute__((ext_vector_type(4))) float f32x4;

#define NB    16
#define DIM   256
#define NTOK  1024

__device__ __forceinline__ u16 f2b(float f) {
    union { float f; uint32_t u; } v; v.f = f;
    uint32_t u = v.u;
    u += 0x7fffu + ((u >> 16) & 1u);
    return (u16)(u >> 16);
}
__device__ __forceinline__ uint32_t pack2(float a, float b) {
    return (uint32_t)f2b(a) | ((uint32_t)f2b(b) << 16);
}
__device__ __forceinline__ f32x4 mfma16(short8 a, short8 b, f32x4 c) {
    return __builtin_amdgcn_mfma_f32_16x16x32_bf16(a, b, c, 0, 0, 0);
}
__device__ __forceinline__ short8 ld8(const u16* p) {
    return *reinterpret_cast<const short8*>(p);
}
__device__ __forceinline__ void gl_lds(const u16* g, u16* l) {
    __builtin_amdgcn_global_load_lds((const __attribute__((address_space(1))) void*)g,
                                     (__attribute__((address_space(3))) void*)l, 16, 0, 0);
}

// ---------------- Kernel 1: pack x -> xbf (bf16, [C][N]) + nodes (bf16 transpose, [N][C])
__global__ __launch_bounds__(256) void pack_kernel(const float* __restrict__ x,
                                                   u16* __restrict__ xbf,
                                                   u16* __restrict__ nodes) {
    __shared__ float tile[64][67];
    int tid = threadIdx.x;
    int blk = blockIdx.x;          // 1024 blocks
    int b  = blk >> 6;
    int t  = blk & 63;
    int c0 = (t >> 4) << 6;
    int n0 = (t & 15) << 6;
    const float* xb = x + (size_t)b * (DIM * NTOK);
    u16* xbb = xbf + (size_t)b * (DIM * NTOK);
#pragma unroll
    for (int i = 0; i < 4; i++) {
        int idx = i * 256 + tid;
        int cl = idx >> 4, nq = idx & 15;
        float4 f = *reinterpret_cast<const float4*>(xb + (size_t)(c0 + cl) * NTOK + n0 + nq * 4);
        tile[cl][nq * 4 + 0] = f.x;
        tile[cl][nq * 4 + 1] = f.y;
        tile[cl][nq * 4 + 2] = f.z;
        tile[cl][nq * 4 + 3] = f.w;
        ushort4 s;
        s.x = f2b(f.x); s.y = f2b(f.y); s.z = f2b(f.z); s.w = f2b(f.w);
        *reinterpret_cast<ushort4*>(xbb + (size_t)(c0 + cl) * NTOK + n0 + nq * 4) = s;
    }
    __syncthreads();
#pragma unroll
    for (int i = 0; i < 4; i++) {
        int idx = i * 256 + tid;
        int nl = idx >> 4, cq = idx & 15;
        ushort4 s;
        s.x = f2b(tile[cq * 4 + 0][nl]);
        s.y = f2b(tile[cq * 4 + 1][nl]);
        s.z = f2b(tile[cq * 4 + 2][nl]);
        s.w = f2b(tile[cq * 4 + 3][nl]);
        *reinterpret_cast<ushort4*>(nodes + (size_t)(b * NTOK + n0 + nl) * DIM + c0 + cq * 4) = s;
    }
}

// ---------------- Kernel 2: convert 3 weight matrices to bf16
__global__ __launch_bounds__(256) void wconv_kernel(const float* __restrict__ a,
                                                    const float* __restrict__ b,
                                                    const float* __restrict__ c,
                                                    u16* __restrict__ o) {
    int i = blockIdx.x * 256 + threadIdx.x;
    const float* s = (i < 65536) ? a : (i < 131072) ? b : c;
    o[i] = f2b(s[i & 65535]);
}

// ---------------- Kernel 3: q = nodes @ proj_w^T + proj_b. 4-way column split:
// grid 1024 (4 blocks/CU -> 16 waves/CU = 4/SIMD), wave = 16 rows x 64 cols.
__global__ __launch_bounds__(256) void proj_kernel(const u16* __restrict__ nodes,
                                                   const u16* __restrict__ wbf,
                                                   const float* __restrict__ pb,
                                                   u16* __restrict__ qb) {
    int lane = threadIdx.x & 63;
    int w = threadIdx.x >> 6;
    int lo = lane & 15, hi = lane >> 4;
    int ch = blockIdx.x & 3;               // column quarter
    int row0 = (blockIdx.x >> 2) * 64 + w * 16;
    const u16* arow = nodes + (size_t)(row0 + lo) * DIM + hi * 8;
    f32x4 acc[4];
#pragma unroll
    for (int i = 0; i < 4; i++) acc[i] = (f32x4){0.f, 0.f, 0.f, 0.f};
#pragma unroll
    for (int t = 0; t < 8; t++) {
        short8 a = ld8(arow + t * 32);
#pragma unroll
        for (int nf = 0; nf < 4; nf++) {
            short8 bfr = ld8(wbf + ((ch * 4 + nf) * 16 + lo) * DIM + t * 32 + hi * 8);
            acc[nf] = mfma16(a, bfr, acc[nf]);
        }
    }
#pragma unroll
    for (int nf = 0; nf < 4; nf++) {
        int col = (ch * 4 + nf) * 16 + lo;
        float bias = pb[col];
#pragma unroll
        for (int r = 0; r < 4; r++) {
            int row = row0 + hi * 4 + r;
            qb[(size_t)row * DIM + col] = f2b(acc[nf][r] + bias);
        }
    }
}

// ---------------- Kernel 4: flash attention (round-5 proven version).
// 256 blocks = 16 q-blocks x 16 batches; 4 waves x 16 q-rows. KV in 64-row
// tiles staged via global_load_lds (pre-swizzled source), double-buffered.
__global__ __launch_bounds__(256) void attn_kernel(const u16* __restrict__ qb,
                                                   const u16* __restrict__ xbf,
                                                   u16* __restrict__ agg) {
    __shared__ u16 kls[2][16384];   // [buf][64 kv rows x 256 ch], rows 512B, slot^=(row&7)
    __shared__ u16 vls[2][16384];   // [buf][256 ch x 64 kv],     rows 128B, slot^=(c&7)

    int lane = threadIdx.x & 63;
    int w = threadIdx.x >> 6;            // 0..3
    int lo = lane & 15, hi = lane >> 4;
    int b  = blockIdx.x & 15;            // batch-per-XCD mapping
    int qt = blockIdx.x >> 4;            // 0..15
    int q0 = qt * 64 + w * 16;
    const u16* qbb = qb  + (size_t)b * (NTOK * DIM);
    const u16* xbb = xbf + (size_t)b * (DIM * NTOK);

    // per-lane staging source offsets (element units), loop-invariant
    int kOff[8], vOff[8];
#pragma unroll
    for (int ii = 0; ii < 8; ii++) {
        int i = w * 8 + ii;
        int krow = 2 * i + (lane >> 5);
        int kslot = (lane & 31) ^ (krow & 7);
        kOff[ii] = krow * DIM + kslot * 8;
        int vc = 8 * i + (lane >> 3);
        int vs = (lane & 7) ^ (vc & 7);
        vOff[ii] = vc * NTOK + vs * 8;
    }

    short8 bq[8];
#pragma unroll
    for (int t = 0; t < 8; t++)
        bq[t] = ld8(qbb + (size_t)(q0 + lo) * DIM + t * 32 + hi * 8);

    f32x4 acc[16];
#pragma unroll
    for (int i = 0; i < 16; i++) acc[i] = (f32x4){0.f, 0.f, 0.f, 0.f};
    float m = -1e30f, ell = 0.f;
    const float C1 = 0.0625f * 1.44269504f;
    const float THR = 11.5f;

    // prologue: stage tile 0 into buf 0
#pragma unroll
    for (int ii = 0; ii < 8; ii++) {
        gl_lds(qbb + kOff[ii], &kls[0][(w * 8 + ii) * 512]);
        gl_lds(xbb + vOff[ii], &vls[0][(w * 8 + ii) * 512]);
    }
    __syncthreads();

    for (int tt = 0; tt < 16; tt++) {
        int buf = tt & 1;
        if (tt < 15) {
            int kvE = (tt + 1) * 64;
#pragma unroll
            for (int ii = 0; ii < 8; ii++) {
                gl_lds(qbb + kvE * DIM + kOff[ii], &kls[buf ^ 1][(w * 8 + ii) * 512]);
                gl_lds(xbb + kvE       + vOff[ii], &vls[buf ^ 1][(w * 8 + ii) * 512]);
            }
        }
        const u16* kb = &kls[buf][0];
        const u16* vb = &vls[buf][0];

        // QK^T: 4 score frags, kv = 64 rows
        f32x4 sfr[4];
#pragma unroll
        for (int s = 0; s < 4; s++) sfr[s] = (f32x4){0.f, 0.f, 0.f, 0.f};
#pragma unroll
        for (int t = 0; t < 8; t++) {
            int sl = ((t * 4 + hi) ^ (lo & 7)) * 8;
#pragma unroll
            for (int s = 0; s < 4; s++) {
                short8 a = ld8(kb + (s * 16 + lo) * DIM + sl);
                sfr[s] = mfma16(a, bq[t], sfr[s]);
            }
        }

        float p[16];
        float pm = -1e30f;
#pragma unroll
        for (int s = 0; s < 4; s++)
#pragma unroll
            for (int r = 0; r < 4; r++) {
                p[s * 4 + r] = sfr[s][r] * C1;
                pm = fmaxf(pm, p[s * 4 + r]);
            }
        pm = fmaxf(pm, __shfl_xor(pm, 16));
        pm = fmaxf(pm, __shfl_xor(pm, 32));
        if (!__all(pm <= m + THR)) {
            float mnew = fmaxf(m, pm);
            float sc = exp2f(m - mnew);
            ell *= sc;
#pragma unroll
            for (int i = 0; i < 16; i++) {
                acc[i][0] *= sc; acc[i][1] *= sc; acc[i][2] *= sc; acc[i][3] *= sc;
            }
            m = mnew;
        }
        float psum = 0.f;
#pragma unroll
        for (int i = 0; i < 16; i++) {
            p[i] = exp2f(p[i] - m);
            psum += p[i];
        }
        psum += __shfl_xor(psum, 16);
        psum += __shfl_xor(psum, 32);
        ell += psum;

        // redistribute P into B-frag layout, one frag per 32-kv half
        short8 pfrag[2];
#pragma unroll
        for (int h = 0; h < 2; h++) {
            uint32_t pl0 = pack2(p[h * 8 + 0], p[h * 8 + 1]);
            uint32_t ph0 = pack2(p[h * 8 + 2], p[h * 8 + 3]);
            uint32_t pl1 = pack2(p[h * 8 + 4], p[h * 8 + 5]);
            uint32_t ph1 = pack2(p[h * 8 + 6], p[h * 8 + 7]);
            int srcA = ((hi & 1) << 5) | lo;
            int srcB = srcA + 16;
            uint32_t w0a = __shfl(pl0, srcA), w0b = __shfl(pl1, srcA);
            uint32_t w1a = __shfl(ph0, srcA), w1b = __shfl(ph1, srcA);
            uint32_t w2a = __shfl(pl0, srcB), w2b = __shfl(pl1, srcB);
            uint32_t w3a = __shfl(ph0, srcB), w3b = __shfl(ph1, srcB);
            bool sel = (hi >= 2);
            union { uint32_t u[4]; short8 v; } pu;
            pu.u[0] = sel ? w0b : w0a;
            pu.u[1] = sel ? w1b : w1a;
            pu.u[2] = sel ? w2b : w2a;
            pu.u[3] = sel ? w3b : w3a;
            pfrag[h] = pu.v;
        }

        // PV: acc[mf] += V^T-frag x P-frag, two 32-kv k-steps
#pragma unroll
        for (int h = 0; h < 2; h++) {
            int sl = ((h * 4 + hi) ^ (lo & 7)) * 8;
#pragma unroll
            for (int mf = 0; mf < 16; mf++) {
                short8 a = ld8(vb + (mf * 16 + lo) * 64 + sl);
                acc[mf] = mfma16(a, pfrag[h], acc[mf]);
            }
        }
        __syncthreads();
    }

    float rinv = 1.f / ell;
#pragma unroll
    for (int mf = 0; mf < 16; mf++) {
        ushort4 st;
        st.x = f2b(acc[mf][0] * rinv);
        st.y = f2b(acc[mf][1] * rinv);
        st.z = f2b(acc[mf][2] * rinv);
        st.w = f2b(acc[mf][3] * rinv);
        *reinterpret_cast<ushort4*>(agg + (size_t)(b * NTOK + q0 + lo) * DIM + mf * 16 + hi * 4) = st;
    }
}

// ---------------- Kernel 5: FFN + residual. Row-split: 512 blocks x 32 rows,
// 8 waves = 2 rowtiles x 4 colquarters (2 blocks/CU -> 16 waves/CU = 4/SIMD).
__global__ __launch_bounds__(512) void ffn_kernel(const u16* __restrict__ agg,
                                                  const u16* __restrict__ wbf,
                                                  const float* __restrict__ b1,
                                                  const float* __restrict__ b2,
                                                  const float* __restrict__ x,
                                                  float* __restrict__ out) {
    __shared__ u16 hl[32][264];
    int lane = threadIdx.x & 63;
    int w = threadIdx.x >> 6;        // 0..7
    int wr = w & 1, wc = w >> 1;     // rowtile, colquarter
    int lo = lane & 15, hi = lane >> 4;
    int row0 = blockIdx.x * 32;      // 512 blocks
    int rw = row0 + wr * 16;
    const u16* w1b = wbf + 65536;
    const u16* w2b = wbf + 131072;

    f32x4 acc[4];
#pragma unroll
    for (int i = 0; i < 4; i++) acc[i] = (f32x4){0.f, 0.f, 0.f, 0.f};
    const u16* arow = agg + (size_t)(rw + lo) * DIM + hi * 8;
#pragma unroll
    for (int t = 0; t < 8; t++) {
        short8 a = ld8(arow + t * 32);
#pragma unroll
        for (int nf = 0; nf < 4; nf++) {
            short8 bfr = ld8(w1b + ((wc * 4 + nf) * 16 + lo) * DIM + t * 32 + hi * 8);
            acc[nf] = mfma16(a, bfr, acc[nf]);
        }
    }
#pragma unroll
    for (int nf = 0; nf < 4; nf++) {
        int f = (wc * 4 + nf) * 16 + lo;
        float bias = b1[f];
#pragma unroll
        for (int r = 0; r < 4; r++) {
            float v = acc[nf][r] + bias;
            float g = 0.5f * v * (1.f + erff(v * 0.70710678f));
            hl[wr * 16 + hi * 4 + r][f] = f2b(g);
        }
    }
    __syncthreads();

    f32x4 acc2[4];
#pragma unroll
    for (int i = 0; i < 4; i++) acc2[i] = (f32x4){0.f, 0.f, 0.f, 0.f};
#pragma unroll
    for (int t = 0; t < 8; t++) {
        short8 bh = ld8(&hl[wr * 16 + lo][t * 32 + hi * 8]);
#pragma unroll
        for (int mf = 0; mf < 4; mf++) {
            short8 a = ld8(w2b + ((wc * 4 + mf) * 16 + lo) * DIM + t * 32 + hi * 8);
            acc2[mf] = mfma16(a, bh, acc2[mf]);
        }
    }
    int bidx = row0 >> 10;
    int n = (rw & 1023) + lo;
#pragma unroll
    for (int mf = 0; mf < 4; mf++) {
#pragma unroll
        for (int r = 0; r < 4; r++) {
            int co = (wc * 4 + mf) * 16 + hi * 4 + r;
            size_t addr = (size_t)bidx * (DIM * NTOK) + (size_t)co * NTOK + n;
            out[addr] = acc2[mf][r] + b2[co] + x[addr];
        }
    }
}

extern "C" void kernel_launch(void* const* d_in, const int* in_sizes, int n_in,
                              void* d_out, int out_size, void* d_ws, size_t ws_size,
                              hipStream_t stream) {
    const float* x      = (const float*)d_in[0];
    const float* proj_w = (const float*)d_in[1];
    const float* proj_b = (const float*)d_in[2];
    const float* w1     = (const float*)d_in[3];
    const float* b1     = (const float*)d_in[4];
    const float* w2     = (const float*)d_in[5];
    const float* b2     = (const float*)d_in[6];
    float* out = (float*)d_out;

    u16* xbf   = (u16*)d_ws;
    u16* nodes = xbf   + 4194304;
    u16* qb    = nodes + 4194304;
    u16* agg   = qb    + 4194304;
    u16* wbf   = agg   + 4194304;

    pack_kernel <<<1024, 256, 0, stream>>>(x, xbf, nodes);
    wconv_kernel<<<768,  256, 0, stream>>>(proj_w, w1, w2, wbf);
    proj_kernel <<<1024, 256, 0, stream>>>(nodes, wbf, proj_b, qb);
    attn_kernel <<<256,  256, 0, stream>>>(qb, xbf, agg);
    ffn_kernel  <<<512,  512, 0, stream>>>(agg, wbf, b1, b2, x, out);
}

// Round 10
// 105.373 us; speedup vs baseline: 1.2570x; 1.1029x over previous
//
#include <hip/hip_runtime.h>
#include <stdint.h>

typedef unsigned short u16;
typedef __attribute__((ext_vector_type(8))) short short8;
typedef __attribute__((ext_vector_type(4))) float f32x4;

#define NB    16
#define DIM   256
#define NTOK  1024

__device__ __forceinline__ u16 f2b(float f) {
    union { float f; uint32_t u; } v; v.f = f;
    uint32_t u = v.u;
    u += 0x7fffu + ((u >> 16) & 1u);
    return (u16)(u >> 16);
}
__device__ __forceinline__ uint32_t pack2(float a, float b) {
    return (uint32_t)f2b(a) | ((uint32_t)f2b(b) << 16);
}
__device__ __forceinline__ f32x4 mfma16(short8 a, short8 b, f32x4 c) {
    return __builtin_amdgcn_mfma_f32_16x16x32_bf16(a, b, c, 0, 0, 0);
}
__device__ __forceinline__ short8 ld8(const u16* p) {
    return *reinterpret_cast<const short8*>(p);
}
__device__ __forceinline__ void gl_lds(const u16* g, u16* l) {
    __builtin_amdgcn_global_load_lds((const __attribute__((address_space(1))) void*)g,
                                     (__attribute__((address_space(3))) void*)l, 16, 0, 0);
}

// ---------------- Kernel 1: pack x -> xbf + nodes; blocks >=1024 convert weights.
__global__ __launch_bounds__(256) void pack_kernel(const float* __restrict__ x,
                                                   u16* __restrict__ xbf,
                                                   u16* __restrict__ nodes,
                                                   const float* __restrict__ pw,
                                                   const float* __restrict__ w1,
                                                   const float* __restrict__ w2,
                                                   u16* __restrict__ wbf) {
    __shared__ float tile[64][67];
    int tid = threadIdx.x;
    int blk = blockIdx.x;
    if (blk >= 1024) {               // weight conversion: 96 blocks x 2048 elems
        int e = (blk - 1024) * 2048 + tid * 8;
        const float* s; int off;
        if (e < 65536)       { s = pw; off = e; }
        else if (e < 131072) { s = w1; off = e - 65536; }
        else                 { s = w2; off = e - 131072; }
        float4 f0 = *reinterpret_cast<const float4*>(s + off);
        float4 f1 = *reinterpret_cast<const float4*>(s + off + 4);
        ushort4 a, bb;
        a.x = f2b(f0.x); a.y = f2b(f0.y); a.z = f2b(f0.z); a.w = f2b(f0.w);
        bb.x = f2b(f1.x); bb.y = f2b(f1.y); bb.z = f2b(f1.z); bb.w = f2b(f1.w);
        *reinterpret_cast<ushort4*>(wbf + e)     = a;
        *reinterpret_cast<ushort4*>(wbf + e + 4) = bb;
        return;
    }
    int b  = blk >> 6;
    int t  = blk & 63;
    int c0 = (t >> 4) << 6;
    int n0 = (t & 15) << 6;
    const float* xb = x + (size_t)b * (DIM * NTOK);
    u16* xbb = xbf + (size_t)b * (DIM * NTOK);
#pragma unroll
    for (int i = 0; i < 4; i++) {
        int idx = i * 256 + tid;
        int cl = idx >> 4, nq = idx & 15;
        float4 f = *reinterpret_cast<const float4*>(xb + (size_t)(c0 + cl) * NTOK + n0 + nq * 4);
        tile[cl][nq * 4 + 0] = f.x;
        tile[cl][nq * 4 + 1] = f.y;
        tile[cl][nq * 4 + 2] = f.z;
        tile[cl][nq * 4 + 3] = f.w;
        ushort4 s;
        s.x = f2b(f.x); s.y = f2b(f.y); s.z = f2b(f.z); s.w = f2b(f.w);
        *reinterpret_cast<ushort4*>(xbb + (size_t)(c0 + cl) * NTOK + n0 + nq * 4) = s;
    }
    __syncthreads();
#pragma unroll
    for (int i = 0; i < 4; i++) {
        int idx = i * 256 + tid;
        int nl = idx >> 4, cq = idx & 15;
        ushort4 s;
        s.x = f2b(tile[cq * 4 + 0][nl]);
        s.y = f2b(tile[cq * 4 + 1][nl]);
        s.z = f2b(tile[cq * 4 + 2][nl]);
        s.w = f2b(tile[cq * 4 + 3][nl]);
        *reinterpret_cast<ushort4*>(nodes + (size_t)(b * NTOK + n0 + nl) * DIM + c0 + cq * 4) = s;
    }
}

// ---------------- Kernel 2: q = nodes @ proj_w^T + proj_b. 4-way column split.
__global__ __launch_bounds__(256) void proj_kernel(const u16* __restrict__ nodes,
                                                   const u16* __restrict__ wbf,
                                                   const float* __restrict__ pb,
                                                   u16* __restrict__ qb) {
    int lane = threadIdx.x & 63;
    int w = threadIdx.x >> 6;
    int lo = lane & 15, hi = lane >> 4;
    int ch = blockIdx.x & 3;
    int row0 = (blockIdx.x >> 2) * 64 + w * 16;
    const u16* arow = nodes + (size_t)(row0 + lo) * DIM + hi * 8;
    f32x4 acc[4];
#pragma unroll
    for (int i = 0; i < 4; i++) acc[i] = (f32x4){0.f, 0.f, 0.f, 0.f};
#pragma unroll
    for (int t = 0; t < 8; t++) {
        short8 a = ld8(arow + t * 32);
#pragma unroll
        for (int nf = 0; nf < 4; nf++) {
            short8 bfr = ld8(wbf + ((ch * 4 + nf) * 16 + lo) * DIM + t * 32 + hi * 8);
            acc[nf] = mfma16(a, bfr, acc[nf]);
        }
    }
#pragma unroll
    for (int nf = 0; nf < 4; nf++) {
        int col = (ch * 4 + nf) * 16 + lo;
        float bias = pb[col];
#pragma unroll
        for (int r = 0; r < 4; r++) {
            int row = row0 + hi * 4 + r;
            qb[(size_t)row * DIM + col] = f2b(acc[nf][r] + bias);
        }
    }
}

// ---------------- Kernel 3: fused attention + FFN + residual.
// 256 blocks (16 qb x 16 batch) x 512 thr = 8 waves: (qsel 0..3) x (kvh 0..1).
// Each kv-stream stages its 512-row range in 32-row tiles (dbuf); 2 waves/SIMD.
// In-block 2-way combine (static acc indices, wave-uniform branch), agg kept in
// LDS, then FFN (GEMM1+GELU+GEMM2) + residual in the same block.
__global__ __launch_bounds__(512, 2) void attn_ffn_kernel(const u16* __restrict__ qb,
                                                          const u16* __restrict__ xbf,
                                                          const u16* __restrict__ wbf,
                                                          const float* __restrict__ b1,
                                                          const float* __restrict__ b2,
                                                          const float* __restrict__ x,
                                                          float* __restrict__ out) {
    __shared__ u16 kls[2][2][8192];   // [stream][buf][32 rows x 256 ch]  64 KB
    __shared__ u16 vls[2][2][8192];   // [stream][buf][256 ch x 32 kv]    64 KB
    __shared__ float2 mell[8][16];

    int lane = threadIdx.x & 63;
    int w = threadIdx.x >> 6;            // 0..7
    int qsel = w >> 1, kvh = w & 1;
    int lo = lane & 15, hi = lane >> 4;
    int b  = blockIdx.x & 15;
    int qt = blockIdx.x >> 4;            // 0..15
    int q0 = qt * 64 + qsel * 16;
    const u16* qbb = qb  + (size_t)b * (NTOK * DIM);
    const u16* xbb = xbf + (size_t)b * (DIM * NTOK);
    const u16* w1b = wbf + 65536;
    const u16* w2b = wbf + 131072;

    // staging offsets (tile-relative, pre-swizzled source)
    int kOff[4], vOff[4], kDst[4], vDst[4];
#pragma unroll
    for (int i = 0; i < 4; i++) {
        int kr = qsel * 8 + i * 2 + (lane >> 5);            // row in 32-row tile
        kOff[i] = kr * DIM + ((lane & 31) ^ (kr & 7)) * 8;
        kDst[i] = (qsel * 8 + i * 2) * 256;
        int vc = qsel * 64 + i * 16 + (lane >> 2);          // channel
        vOff[i] = vc * NTOK + ((lane & 3) ^ (vc & 3)) * 8;  // + kv base at use
        vDst[i] = (qsel * 64 + i * 16) * 32;
    }
    int kvbeg = kvh * 512;

    short8 bq[8];
#pragma unroll
    for (int t = 0; t < 8; t++)
        bq[t] = ld8(qbb + (size_t)(q0 + lo) * DIM + t * 32 + hi * 8);

    f32x4 acc[16];
#pragma unroll
    for (int i = 0; i < 16; i++) acc[i] = (f32x4){0.f, 0.f, 0.f, 0.f};
    float m = -1e30f, ell = 0.f;
    const float C1 = 0.0625f * 1.44269504f;
    const float THR = 11.5f;

    // prologue: stage tile 0 of this stream
#pragma unroll
    for (int i = 0; i < 4; i++) {
        gl_lds(qbb + kvbeg * DIM + kOff[i], &kls[kvh][0][kDst[i]]);
        gl_lds(xbb + kvbeg       + vOff[i], &vls[kvh][0][vDst[i]]);
    }
    __syncthreads();

    for (int tt = 0; tt < 16; tt++) {
        int buf = tt & 1;
        if (tt < 15) {
            int base = (tt + 1) * 32;
#pragma unroll
            for (int i = 0; i < 4; i++) {
                gl_lds(qbb + (kvbeg + base) * DIM + kOff[i], &kls[kvh][buf ^ 1][kDst[i]]);
                gl_lds(xbb + kvbeg + base        + vOff[i], &vls[kvh][buf ^ 1][vDst[i]]);
            }
        }
        const u16* kb = &kls[kvh][buf][0];
        const u16* vb = &vls[kvh][buf][0];

        // QK^T: 2 score frags (tile kv rows 0..15, 16..31)
        f32x4 s0 = (f32x4){0.f, 0.f, 0.f, 0.f};
        f32x4 s1 = (f32x4){0.f, 0.f, 0.f, 0.f};
        __builtin_amdgcn_s_setprio(1);
#pragma unroll
        for (int t = 0; t < 8; t++) {
            int sl = ((t * 4 + hi) ^ (lo & 7)) * 8;
            s0 = mfma16(ld8(kb + lo * 256 + sl),        bq[t], s0);
            s1 = mfma16(ld8(kb + (16 + lo) * 256 + sl), bq[t], s1);
        }
        __builtin_amdgcn_s_setprio(0);

        float p0[4], p1[4];
        float pm = -1e30f;
#pragma unroll
        for (int r = 0; r < 4; r++) {
            p0[r] = s0[r] * C1;
            p1[r] = s1[r] * C1;
            pm = fmaxf(pm, fmaxf(p0[r], p1[r]));
        }
        pm = fmaxf(pm, __shfl_xor(pm, 16));
        pm = fmaxf(pm, __shfl_xor(pm, 32));
        if (!__all(pm <= m + THR)) {
            float mnew = fmaxf(m, pm);
            float sc = exp2f(m - mnew);
            ell *= sc;
#pragma unroll
            for (int i = 0; i < 16; i++) {
                acc[i][0] *= sc; acc[i][1] *= sc; acc[i][2] *= sc; acc[i][3] *= sc;
            }
            m = mnew;
        }
        float psum = 0.f;
#pragma unroll
        for (int r = 0; r < 4; r++) {
            p0[r] = exp2f(p0[r] - m);
            p1[r] = exp2f(p1[r] - m);
            psum += p0[r] + p1[r];
        }
        psum += __shfl_xor(psum, 16);
        psum += __shfl_xor(psum, 32);
        ell += psum;

        // redistribute P (lane: P[q=lo][kv=4*hi+r (+16)]) into one B-frag (32 kv)
        uint32_t pl0 = pack2(p0[0], p0[1]), ph0 = pack2(p0[2], p0[3]);
        uint32_t pl1 = pack2(p1[0], p1[1]), ph1 = pack2(p1[2], p1[3]);
        int srcA = ((hi & 1) << 5) | lo;
        int srcB = srcA + 16;
        uint32_t w0a = __shfl(pl0, srcA), w0b = __shfl(pl1, srcA);
        uint32_t w1a = __shfl(ph0, srcA), w1b = __shfl(ph1, srcA);
        uint32_t w2a = __shfl(pl0, srcB), w2b = __shfl(pl1, srcB);
        uint32_t w3a = __shfl(ph0, srcB), w3b = __shfl(ph1, srcB);
        bool sel = (hi >= 2);
        union { uint32_t u[4]; short8 v; } pu;
        pu.u[0] = sel ? w0b : w0a;
        pu.u[1] = sel ? w1b : w1a;
        pu.u[2] = sel ? w2b : w2a;
        pu.u[3] = sel ? w3b : w3a;
        short8 pfrag = pu.v;

        // PV: one 32-kv k-step
        int vsl = (hi ^ (lo & 3)) * 8;
        __builtin_amdgcn_s_setprio(1);
#pragma unroll
        for (int mf = 0; mf < 16; mf++) {
            short8 a = ld8(vb + (mf * 16 + lo) * 32 + vsl);
            acc[mf] = mfma16(a, pfrag, acc[mf]);
        }
        __builtin_amdgcn_s_setprio(0);
        __syncthreads();
    }

    // ---- 2-way combine across kv-halves (partner = w^1), static indices ----
    if (lane < 16) mell[w][lane] = make_float2(m, ell);
    __syncthreads();
    float2 op = mell[w ^ 1][lo];
    float M = fmaxf(m, op.x);
    float mysc = exp2f(m - M);
    float wsum = ell * mysc + op.y * exp2f(op.x - M);
    float rinv = 1.f / wsum;
#pragma unroll
    for (int i = 0; i < 16; i++) {
        acc[i][0] *= mysc; acc[i][1] *= mysc; acc[i][2] *= mysc; acc[i][3] *= mysc;
    }
    char* pbase = (char*)kls;   // 64 KB scratch for giveaway halves
    if (kvh == 0) {
#pragma unroll
        for (int j = 0; j < 8; j++) {
            int byte = w * 8192 + lo * 512 + ((j * 64 + hi * 16) ^ ((lo & 7) << 4));
            *reinterpret_cast<f32x4*>(pbase + byte) = acc[8 + j];
        }
    } else {
#pragma unroll
        for (int j = 0; j < 8; j++) {
            int byte = w * 8192 + lo * 512 + ((j * 64 + hi * 16) ^ ((lo & 7) << 4));
            *reinterpret_cast<f32x4*>(pbase + byte) = acc[j];
        }
    }
    __syncthreads();
    // add partner's giveaway to kept half; write agg tile (bf16, swizzled) in vls
    char* abase = (char*)vls;   // agg tile [64][256] u16, row 512B, slot^=(row&7)
    int arow = qsel * 16 + lo;
    if (kvh == 0) {
#pragma unroll
        for (int j = 0; j < 8; j++) {
            int byte = (w ^ 1) * 8192 + lo * 512 + ((j * 64 + hi * 16) ^ ((lo & 7) << 4));
            f32x4 o = *reinterpret_cast<const f32x4*>(pbase + byte);
            uint32_t lo32 = pack2((acc[j][0] + o[0]) * rinv, (acc[j][1] + o[1]) * rinv);
            uint32_t hi32 = pack2((acc[j][2] + o[2]) * rinv, (acc[j][3] + o[3]) * rinv);
            int slot = j * 2 + (hi >> 1);                    // ch half 0
            int byteA = arow * 512 + ((slot ^ (lo & 7)) * 16) + (hi & 1) * 8;
            *reinterpret_cast<uint32_t*>(abase + byteA)     = lo32;
            *reinterpret_cast<uint32_t*>(abase + byteA + 4) = hi32;
        }
    } else {
#pragma unroll
        for (int j = 0; j < 8; j++) {
            int byte = (w ^ 1) * 8192 + lo * 512 + ((j * 64 + hi * 16) ^ ((lo & 7) << 4));
            f32x4 o = *reinterpret_cast<const f32x4*>(pbase + byte);
            uint32_t lo32 = pack2((acc[8 + j][0] + o[0]) * rinv, (acc[8 + j][1] + o[1]) * rinv);
            uint32_t hi32 = pack2((acc[8 + j][2] + o[2]) * rinv, (acc[8 + j][3] + o[3]) * rinv);
            int slot = 16 + j * 2 + (hi >> 1);               // ch half 1
            int byteA = arow * 512 + ((slot ^ (lo & 7)) * 16) + (hi & 1) * 8;
            *reinterpret_cast<uint32_t*>(abase + byteA)     = lo32;
            *reinterpret_cast<uint32_t*>(abase + byteA + 4) = hi32;
        }
    }
    __syncthreads();

    // ---- FFN on this block's 64 rows: 8 waves = 4 rowtiles x 2 colhalves ----
    int wr = w & 3, wc = w >> 2;
    f32x4 acc1[8];
#pragma unroll
    for (int i = 0; i < 8; i++) acc1[i] = (f32x4){0.f, 0.f, 0.f, 0.f};
#pragma unroll
    for (int t = 0; t < 8; t++) {
        int byteA = (wr * 16 + lo) * 512 + (((t * 4 + hi) ^ (lo & 7)) * 16);
        short8 a = *reinterpret_cast<const short8*>(abase + byteA);
#pragma unroll
        for (int nf = 0; nf < 8; nf++) {
            short8 bfr = ld8(w1b + ((wc * 8 + nf) * 16 + lo) * DIM + t * 32 + hi * 8);
            acc1[nf] = mfma16(a, bfr, acc1[nf]);
        }
    }
    u16* hl = (u16*)kls;   // [64][264]
#pragma unroll
    for (int nf = 0; nf < 8; nf++) {
        int f = (wc * 8 + nf) * 16 + lo;
        float bias = b1[f];
#pragma unroll
        for (int r = 0; r < 4; r++) {
            float v = acc1[nf][r] + bias;
            float g = 0.5f * v * (1.f + erff(v * 0.70710678f));
            hl[(wr * 16 + hi * 4 + r) * 264 + f] = f2b(g);
        }
    }
    __syncthreads();

    f32x4 acc2[8];
#pragma unroll
    for (int i = 0; i < 8; i++) acc2[i] = (f32x4){0.f, 0.f, 0.f, 0.f};
#pragma unroll
    for (int t = 0; t < 8; t++) {
        short8 bh = ld8(hl + (wr * 16 + lo) * 264 + t * 32 + hi * 8);
#pragma unroll
        for (int mf = 0; mf < 8; mf++) {
            short8 a2 = ld8(w2b + ((wc * 8 + mf) * 16 + lo) * DIM + t * 32 + hi * 8);
            acc2[mf] = mfma16(a2, bh, acc2[mf]);
        }
    }
    int n = qt * 64 + wr * 16 + lo;
#pragma unroll
    for (int mf = 0; mf < 8; mf++) {
#pragma unroll
        for (int r = 0; r < 4; r++) {
            int co = (wc * 8 + mf) * 16 + hi * 4 + r;
            size_t addr = (size_t)b * (DIM * NTOK) + (size_t)co * NTOK + n;
            out[addr] = acc2[mf][r] + b2[co] + x[addr];
        }
    }
}

extern "C" void kernel_launch(void* const* d_in, const int* in_sizes, int n_in,
                              void* d_out, int out_size, void* d_ws, size_t ws_size,
                              hipStream_t stream) {
    const float* x      = (const float*)d_in[0];
    const float* proj_w = (const float*)d_in[1];
    const float* proj_b = (const float*)d_in[2];
    const float* w1     = (const float*)d_in[3];
    const float* b1     = (const float*)d_in[4];
    const float* w2     = (const float*)d_in[5];
    const float* b2     = (const float*)d_in[6];
    float* out = (float*)d_out;

    u16* xbf   = (u16*)d_ws;
    u16* nodes = xbf   + 4194304;
    u16* qb    = nodes + 4194304;
    u16* wbf   = qb    + 4194304;

    pack_kernel    <<<1120, 256, 0, stream>>>(x, xbf, nodes, proj_w, w1, w2, wbf);
    proj_kernel    <<<1024, 256, 0, stream>>>(nodes, wbf, proj_b, qb);
    attn_ffn_kernel<<<256,  512, 0, stream>>>(qb, xbf, wbf, b1, b2, x, out);
}

// Round 11
// 103.224 us; speedup vs baseline: 1.2831x; 1.0208x over previous
//
#include <hip/hip_runtime.h>
#include <stdint.h>

typedef unsigned short u16;
typedef __attribute__((ext_vector_type(8))) short short8;
typedef __attribute__((ext_vector_type(4))) float f32x4;

#define NB    16
#define DIM   256
#define NTOK  1024

__device__ __forceinline__ u16 f2b(float f) {
    union { float f; uint32_t u; } v; v.f = f;
    uint32_t u = v.u;
    u += 0x7fffu + ((u >> 16) & 1u);
    return (u16)(u >> 16);
}
__device__ __forceinline__ uint32_t pack2(float a, float b) {
    return (uint32_t)f2b(a) | ((uint32_t)f2b(b) << 16);
}
__device__ __forceinline__ f32x4 mfma16(short8 a, short8 b, f32x4 c) {
    return __builtin_amdgcn_mfma_f32_16x16x32_bf16(a, b, c, 0, 0, 0);
}
__device__ __forceinline__ short8 ld8(const u16* p) {
    return *reinterpret_cast<const short8*>(p);
}
__device__ __forceinline__ void gl_lds(const u16* g, u16* l) {
    __builtin_amdgcn_global_load_lds((const __attribute__((address_space(1))) void*)g,
                                     (__attribute__((address_space(3))) void*)l, 16, 0, 0);
}

// ---------------- Kernel 1: pack x -> xbf + nodes; blocks >=1024 convert weights.
__global__ __launch_bounds__(256) void pack_kernel(const float* __restrict__ x,
                                                   u16* __restrict__ xbf,
                                                   u16* __restrict__ nodes,
                                                   const float* __restrict__ pw,
                                                   const float* __restrict__ w1,
                                                   const float* __restrict__ w2,
                                                   u16* __restrict__ wbf) {
    __shared__ float tile[64][67];
    int tid = threadIdx.x;
    int blk = blockIdx.x;
    if (blk >= 1024) {               // weight conversion: 96 blocks x 2048 elems
        int e = (blk - 1024) * 2048 + tid * 8;
        const float* s; int off;
        if (e < 65536)       { s = pw; off = e; }
        else if (e < 131072) { s = w1; off = e - 65536; }
        else                 { s = w2; off = e - 131072; }
        float4 f0 = *reinterpret_cast<const float4*>(s + off);
        float4 f1 = *reinterpret_cast<const float4*>(s + off + 4);
        ushort4 a, bb;
        a.x = f2b(f0.x); a.y = f2b(f0.y); a.z = f2b(f0.z); a.w = f2b(f0.w);
        bb.x = f2b(f1.x); bb.y = f2b(f1.y); bb.z = f2b(f1.z); bb.w = f2b(f1.w);
        *reinterpret_cast<ushort4*>(wbf + e)     = a;
        *reinterpret_cast<ushort4*>(wbf + e + 4) = bb;
        return;
    }
    int b  = blk >> 6;
    int t  = blk & 63;
    int c0 = (t >> 4) << 6;
    int n0 = (t & 15) << 6;
    const float* xb = x + (size_t)b * (DIM * NTOK);
    u16* xbb = xbf + (size_t)b * (DIM * NTOK);
#pragma unroll
    for (int i = 0; i < 4; i++) {
        int idx = i * 256 + tid;
        int cl = idx >> 4, nq = idx & 15;
        float4 f = *reinterpret_cast<const float4*>(xb + (size_t)(c0 + cl) * NTOK + n0 + nq * 4);
        tile[cl][nq * 4 + 0] = f.x;
        tile[cl][nq * 4 + 1] = f.y;
        tile[cl][nq * 4 + 2] = f.z;
        tile[cl][nq * 4 + 3] = f.w;
        ushort4 s;
        s.x = f2b(f.x); s.y = f2b(f.y); s.z = f2b(f.z); s.w = f2b(f.w);
        *reinterpret_cast<ushort4*>(xbb + (size_t)(c0 + cl) * NTOK + n0 + nq * 4) = s;
    }
    __syncthreads();
#pragma unroll
    for (int i = 0; i < 4; i++) {
        int idx = i * 256 + tid;
        int nl = idx >> 4, cq = idx & 15;
        ushort4 s;
        s.x = f2b(tile[cq * 4 + 0][nl]);
        s.y = f2b(tile[cq * 4 + 1][nl]);
        s.z = f2b(tile[cq * 4 + 2][nl]);
        s.w = f2b(tile[cq * 4 + 3][nl]);
        *reinterpret_cast<ushort4*>(nodes + (size_t)(b * NTOK + n0 + nl) * DIM + c0 + cq * 4) = s;
    }
}

// ---------------- Kernel 2: q = nodes @ proj_w^T + proj_b. 4-way column split.
__global__ __launch_bounds__(256) void proj_kernel(const u16* __restrict__ nodes,
                                                   const u16* __restrict__ wbf,
                                                   const float* __restrict__ pb,
                                                   u16* __restrict__ qb) {
    int lane = threadIdx.x & 63;
    int w = threadIdx.x >> 6;
    int lo = lane & 15, hi = lane >> 4;
    int ch = blockIdx.x & 3;
    int row0 = (blockIdx.x >> 2) * 64 + w * 16;
    const u16* arow = nodes + (size_t)(row0 + lo) * DIM + hi * 8;
    f32x4 acc[4];
#pragma unroll
    for (int i = 0; i < 4; i++) acc[i] = (f32x4){0.f, 0.f, 0.f, 0.f};
#pragma unroll
    for (int t = 0; t < 8; t++) {
        short8 a = ld8(arow + t * 32);
#pragma unroll
        for (int nf = 0; nf < 4; nf++) {
            short8 bfr = ld8(wbf + ((ch * 4 + nf) * 16 + lo) * DIM + t * 32 + hi * 8);
            acc[nf] = mfma16(a, bfr, acc[nf]);
        }
    }
#pragma unroll
    for (int nf = 0; nf < 4; nf++) {
        int col = (ch * 4 + nf) * 16 + lo;
        float bias = pb[col];
#pragma unroll
        for (int r = 0; r < 4; r++) {
            int row = row0 + hi * 4 + r;
            qb[(size_t)row * DIM + col] = f2b(acc[nf][r] + bias);
        }
    }
}

// ---------------- Kernel 3: fused attention + FFN. 256 blocks x 256 thr.
// 4 waves = 2 q-tiles(32 rows) x 2 kv-halves. Each wave: 32 q x 512 kv in
// 32-row tiles (dbuf). K/V fragment reads from LDS are REUSED by 2 MFMAs
// (the wave's two 16-row q-frags) -> 2x FLOP per LDS byte vs round 10.
__global__ __launch_bounds__(256, 1) void attn_ffn_kernel(const u16* __restrict__ qb,
                                                          const u16* __restrict__ xbf,
                                                          const u16* __restrict__ wbf,
                                                          const float* __restrict__ b1,
                                                          const float* __restrict__ b2,
                                                          const float* __restrict__ x,
                                                          float* __restrict__ out) {
    __shared__ u16 kls[2][2][8192];   // [stream][buf][32 rows x 256 ch]  64 KB
    __shared__ u16 vls[2][2][8192];   // [stream][buf][256 ch x 32 kv]    64 KB
    __shared__ float2 mell[4][2][16];

    int lane = threadIdx.x & 63;
    int w = threadIdx.x >> 6;            // 0..3
    int qsel = w >> 1, kvh = w & 1;
    int lo = lane & 15, hi = lane >> 4;
    int b  = blockIdx.x & 15;
    int qt = blockIdx.x >> 4;            // 0..15
    int q0 = qt * 64 + qsel * 32;
    const u16* qbb = qb  + (size_t)b * (NTOK * DIM);
    const u16* xbb = xbf + (size_t)b * (DIM * NTOK);
    const u16* w1b = wbf + 65536;
    const u16* w2b = wbf + 131072;

    // staging: stream kvh staged by its 2 waves (qsel 0,1), 8 K + 8 V instr each
    int kOff[8], vOff[8], kDst[8], vDst[8];
#pragma unroll
    for (int i = 0; i < 8; i++) {
        int kr = qsel * 16 + i * 2 + (lane >> 5);
        kOff[i] = kr * DIM + ((lane & 31) ^ (kr & 7)) * 8;
        kDst[i] = (qsel * 16 + i * 2) * 256;
        int vc = qsel * 128 + i * 16 + (lane >> 2);
        vOff[i] = vc * NTOK + ((lane & 3) ^ (vc & 3)) * 8;
        vDst[i] = (qsel * 128 + i * 16) * 32;
    }
    int kvbeg = kvh * 512;

    short8 bq0[8], bq1[8];
#pragma unroll
    for (int t = 0; t < 8; t++) {
        bq0[t] = ld8(qbb + (size_t)(q0 + lo) * DIM + t * 32 + hi * 8);
        bq1[t] = ld8(qbb + (size_t)(q0 + 16 + lo) * DIM + t * 32 + hi * 8);
    }

    f32x4 acc0[16], acc1[16];
#pragma unroll
    for (int i = 0; i < 16; i++) {
        acc0[i] = (f32x4){0.f, 0.f, 0.f, 0.f};
        acc1[i] = (f32x4){0.f, 0.f, 0.f, 0.f};
    }
    float m0 = -1e30f, ell0 = 0.f, m1 = -1e30f, ell1 = 0.f;
    const float C1 = 0.0625f * 1.44269504f;
    const float THR = 11.5f;

    // prologue: stage tile 0 of this stream
#pragma unroll
    for (int i = 0; i < 8; i++) {
        gl_lds(qbb + kvbeg * DIM + kOff[i], &kls[kvh][0][kDst[i]]);
        gl_lds(xbb + kvbeg       + vOff[i], &vls[kvh][0][vDst[i]]);
    }
    __syncthreads();

    for (int tt = 0; tt < 16; tt++) {
        int buf = tt & 1;
        if (tt < 15) {
            int base = kvbeg + (tt + 1) * 32;
#pragma unroll
            for (int i = 0; i < 8; i++) {
                gl_lds(qbb + base * DIM + kOff[i], &kls[kvh][buf ^ 1][kDst[i]]);
                gl_lds(xbb + base       + vOff[i], &vls[kvh][buf ^ 1][vDst[i]]);
            }
        }
        const u16* kb = &kls[kvh][buf][0];
        const u16* vb = &vls[kvh][buf][0];

        // QK^T: 4 score frags = 2 qf x 2 kvf; A-frags read once, used twice
        f32x4 s00 = (f32x4){0.f,0.f,0.f,0.f}, s01 = (f32x4){0.f,0.f,0.f,0.f};
        f32x4 s10 = (f32x4){0.f,0.f,0.f,0.f}, s11 = (f32x4){0.f,0.f,0.f,0.f};
        __builtin_amdgcn_s_setprio(1);
#pragma unroll
        for (int t = 0; t < 8; t++) {
            int sl = ((t * 4 + hi) ^ (lo & 7)) * 8;
            short8 a0 = ld8(kb + lo * 256 + sl);
            short8 a1 = ld8(kb + (16 + lo) * 256 + sl);
            s00 = mfma16(a0, bq0[t], s00);
            s01 = mfma16(a1, bq0[t], s01);
            s10 = mfma16(a0, bq1[t], s10);
            s11 = mfma16(a1, bq1[t], s11);
        }
        __builtin_amdgcn_s_setprio(0);

        // softmax qf=0
        float p00[4], p01[4], p10[4], p11[4];
        float pm0 = -1e30f, pm1 = -1e30f;
#pragma unroll
        for (int r = 0; r < 4; r++) {
            p00[r] = s00[r] * C1; p01[r] = s01[r] * C1;
            p10[r] = s10[r] * C1; p11[r] = s11[r] * C1;
            pm0 = fmaxf(pm0, fmaxf(p00[r], p01[r]));
            pm1 = fmaxf(pm1, fmaxf(p10[r], p11[r]));
        }
        pm0 = fmaxf(pm0, __shfl_xor(pm0, 16));
        pm0 = fmaxf(pm0, __shfl_xor(pm0, 32));
        pm1 = fmaxf(pm1, __shfl_xor(pm1, 16));
        pm1 = fmaxf(pm1, __shfl_xor(pm1, 32));
        if (!__all(pm0 <= m0 + THR)) {
            float mn = fmaxf(m0, pm0);
            float sc = exp2f(m0 - mn);
            ell0 *= sc;
#pragma unroll
            for (int i = 0; i < 16; i++) {
                acc0[i][0] *= sc; acc0[i][1] *= sc; acc0[i][2] *= sc; acc0[i][3] *= sc;
            }
            m0 = mn;
        }
        if (!__all(pm1 <= m1 + THR)) {
            float mn = fmaxf(m1, pm1);
            float sc = exp2f(m1 - mn);
            ell1 *= sc;
#pragma unroll
            for (int i = 0; i < 16; i++) {
                acc1[i][0] *= sc; acc1[i][1] *= sc; acc1[i][2] *= sc; acc1[i][3] *= sc;
            }
            m1 = mn;
        }
        float ps0 = 0.f, ps1 = 0.f;
#pragma unroll
        for (int r = 0; r < 4; r++) {
            p00[r] = exp2f(p00[r] - m0); p01[r] = exp2f(p01[r] - m0);
            p10[r] = exp2f(p10[r] - m1); p11[r] = exp2f(p11[r] - m1);
            ps0 += p00[r] + p01[r];
            ps1 += p10[r] + p11[r];
        }
        ps0 += __shfl_xor(ps0, 16); ps0 += __shfl_xor(ps0, 32);
        ps1 += __shfl_xor(ps1, 16); ps1 += __shfl_xor(ps1, 32);
        ell0 += ps0; ell1 += ps1;

        // redistribute P -> B-frag, per qf (8 shfl each)
        short8 pfrag0, pfrag1;
        {
            uint32_t pl0 = pack2(p00[0], p00[1]), ph0 = pack2(p00[2], p00[3]);
            uint32_t pl1 = pack2(p01[0], p01[1]), ph1 = pack2(p01[2], p01[3]);
            int srcA = ((hi & 1) << 5) | lo;
            int srcB = srcA + 16;
            uint32_t w0a = __shfl(pl0, srcA), w0b = __shfl(pl1, srcA);
            uint32_t w1a = __shfl(ph0, srcA), w1b = __shfl(ph1, srcA);
            uint32_t w2a = __shfl(pl0, srcB), w2b = __shfl(pl1, srcB);
            uint32_t w3a = __shfl(ph0, srcB), w3b = __shfl(ph1, srcB);
            bool sel = (hi >= 2);
            union { uint32_t u[4]; short8 v; } pu;
            pu.u[0] = sel ? w0b : w0a;
            pu.u[1] = sel ? w1b : w1a;
            pu.u[2] = sel ? w2b : w2a;
            pu.u[3] = sel ? w3b : w3a;
            pfrag0 = pu.v;
        }
        {
            uint32_t pl0 = pack2(p10[0], p10[1]), ph0 = pack2(p10[2], p10[3]);
            uint32_t pl1 = pack2(p11[0], p11[1]), ph1 = pack2(p11[2], p11[3]);
            int srcA = ((hi & 1) << 5) | lo;
            int srcB = srcA + 16;
            uint32_t w0a = __shfl(pl0, srcA), w0b = __shfl(pl1, srcA);
            uint32_t w1a = __shfl(ph0, srcA), w1b = __shfl(ph1, srcA);
            uint32_t w2a = __shfl(pl0, srcB), w2b = __shfl(pl1, srcB);
            uint32_t w3a = __shfl(ph0, srcB), w3b = __shfl(ph1, srcB);
            bool sel = (hi >= 2);
            union { uint32_t u[4]; short8 v; } pu;
            pu.u[0] = sel ? w0b : w0a;
            pu.u[1] = sel ? w1b : w1a;
            pu.u[2] = sel ? w2b : w2a;
            pu.u[3] = sel ? w3b : w3a;
            pfrag1 = pu.v;
        }

        // PV: V-frag read once, used by both qf
        int vsl = (hi ^ (lo & 3)) * 8;
        __builtin_amdgcn_s_setprio(1);
#pragma unroll
        for (int mf = 0; mf < 16; mf++) {
            short8 a = ld8(vb + (mf * 16 + lo) * 32 + vsl);
            acc0[mf] = mfma16(a, pfrag0, acc0[mf]);
            acc1[mf] = mfma16(a, pfrag1, acc1[mf]);
        }
        __builtin_amdgcn_s_setprio(0);
        __syncthreads();
    }

    // ---- combine across kv-halves (partner = w^1), static indices ----
    if (lane < 16) {
        mell[w][0][lane] = make_float2(m0, ell0);
        mell[w][1][lane] = make_float2(m1, ell1);
    }
    __syncthreads();
    float2 op0 = mell[w ^ 1][0][lo];
    float2 op1 = mell[w ^ 1][1][lo];
    float M0 = fmaxf(m0, op0.x), M1 = fmaxf(m1, op1.x);
    float sc0 = exp2f(m0 - M0), sc1 = exp2f(m1 - M1);
    float rinv0 = 1.f / (ell0 * sc0 + op0.y * exp2f(op0.x - M0));
    float rinv1 = 1.f / (ell1 * sc1 + op1.y * exp2f(op1.x - M1));
#pragma unroll
    for (int i = 0; i < 16; i++) {
        acc0[i][0] *= sc0; acc0[i][1] *= sc0; acc0[i][2] *= sc0; acc0[i][3] *= sc0;
        acc1[i][0] *= sc1; acc1[i][1] *= sc1; acc1[i][2] *= sc1; acc1[i][3] *= sc1;
    }
    char* pbase = (char*)kls;   // 64 KB giveaway scratch
    if (kvh == 0) {
#pragma unroll
        for (int j = 0; j < 8; j++) {
            int byt = (w * 2 + 0) * 8192 + lo * 512 + ((j * 64 + hi * 16) ^ ((lo & 7) << 4));
            *reinterpret_cast<f32x4*>(pbase + byt) = acc0[8 + j];
            int byt1 = (w * 2 + 1) * 8192 + lo * 512 + ((j * 64 + hi * 16) ^ ((lo & 7) << 4));
            *reinterpret_cast<f32x4*>(pbase + byt1) = acc1[8 + j];
        }
    } else {
#pragma unroll
        for (int j = 0; j < 8; j++) {
            int byt = (w * 2 + 0) * 8192 + lo * 512 + ((j * 64 + hi * 16) ^ ((lo & 7) << 4));
            *reinterpret_cast<f32x4*>(pbase + byt) = acc0[j];
            int byt1 = (w * 2 + 1) * 8192 + lo * 512 + ((j * 64 + hi * 16) ^ ((lo & 7) << 4));
            *reinterpret_cast<f32x4*>(pbase + byt1) = acc1[j];
        }
    }
    __syncthreads();
    char* abase = (char*)vls;   // agg [64][256] bf16, row 512B, granule^=(row&7)
    if (kvh == 0) {
#pragma unroll
        for (int j = 0; j < 8; j++) {
            int pb0 = ((w ^ 1) * 2 + 0) * 8192 + lo * 512 + ((j * 64 + hi * 16) ^ ((lo & 7) << 4));
            f32x4 o = *reinterpret_cast<const f32x4*>(pbase + pb0);
            uint32_t lo32 = pack2((acc0[j][0] + o[0]) * rinv0, (acc0[j][1] + o[1]) * rinv0);
            uint32_t hi32 = pack2((acc0[j][2] + o[2]) * rinv0, (acc0[j][3] + o[3]) * rinv0);
            int slot = j * 2 + (hi >> 1);
            int arow = qsel * 32 + lo;
            int byteA = arow * 512 + ((slot ^ (lo & 7)) * 16) + (hi & 1) * 8;
            *reinterpret_cast<uint32_t*>(abase + byteA)     = lo32;
            *reinterpret_cast<uint32_t*>(abase + byteA + 4) = hi32;
            int pb1 = ((w ^ 1) * 2 + 1) * 8192 + lo * 512 + ((j * 64 + hi * 16) ^ ((lo & 7) << 4));
            f32x4 o1 = *reinterpret_cast<const f32x4*>(pbase + pb1);
            uint32_t lo32b = pack2((acc1[j][0] + o1[0]) * rinv1, (acc1[j][1] + o1[1]) * rinv1);
            uint32_t hi32b = pack2((acc1[j][2] + o1[2]) * rinv1, (acc1[j][3] + o1[3]) * rinv1);
            int arow1 = qsel * 32 + 16 + lo;
            int byteB = arow1 * 512 + ((slot ^ (lo & 7)) * 16) + (hi & 1) * 8;
            *reinterpret_cast<uint32_t*>(abase + byteB)     = lo32b;
            *reinterpret_cast<uint32_t*>(abase + byteB + 4) = hi32b;
        }
    } else {
#pragma unroll
        for (int j = 0; j < 8; j++) {
            int pb0 = ((w ^ 1) * 2 + 0) * 8192 + lo * 512 + ((j * 64 + hi * 16) ^ ((lo & 7) << 4));
            f32x4 o = *reinterpret_cast<const f32x4*>(pbase + pb0);
            uint32_t lo32 = pack2((acc0[8 + j][0] + o[0]) * rinv0, (acc0[8 + j][1] + o[1]) * rinv0);
            uint32_t hi32 = pack2((acc0[8 + j][2] + o[2]) * rinv0, (acc0[8 + j][3] + o[3]) * rinv0);
            int slot = 16 + j * 2 + (hi >> 1);
            int arow = qsel * 32 + lo;
            int byteA = arow * 512 + ((slot ^ (lo & 7)) * 16) + (hi & 1) * 8;
            *reinterpret_cast<uint32_t*>(abase + byteA)     = lo32;
            *reinterpret_cast<uint32_t*>(abase + byteA + 4) = hi32;
            int pb1 = ((w ^ 1) * 2 + 1) * 8192 + lo * 512 + ((j * 64 + hi * 16) ^ ((lo & 7) << 4));
            f32x4 o1 = *reinterpret_cast<const f32x4*>(pbase + pb1);
            uint32_t lo32b = pack2((acc1[8 + j][0] + o1[0]) * rinv1, (acc1[8 + j][1] + o1[1]) * rinv1);
            uint32_t hi32b = pack2((acc1[8 + j][2] + o1[2]) * rinv1, (acc1[8 + j][3] + o1[3]) * rinv1);
            int arow1 = qsel * 32 + 16 + lo;
            int byteB = arow1 * 512 + ((slot ^ (lo & 7)) * 16) + (hi & 1) * 8;
            *reinterpret_cast<uint32_t*>(abase + byteB)     = lo32b;
            *reinterpret_cast<uint32_t*>(abase + byteB + 4) = hi32b;
        }
    }
    __syncthreads();

    // ---- FFN: 4 waves = 2 rowhalves(32) x 2 colhalves(128); weight frags
    // reused across the 2 row-frags.
    int rh = w >> 1, chh = w & 1;
    f32x4 f1a[8], f1b[8];
#pragma unroll
    for (int i = 0; i < 8; i++) {
        f1a[i] = (f32x4){0.f, 0.f, 0.f, 0.f};
        f1b[i] = (f32x4){0.f, 0.f, 0.f, 0.f};
    }
#pragma unroll
    for (int t = 0; t < 8; t++) {
        int g = ((t * 4 + hi) ^ (lo & 7)) * 16;
        short8 aA = *reinterpret_cast<const short8*>(abase + (rh * 32 + lo) * 512 + g);
        short8 aB = *reinterpret_cast<const short8*>(abase + (rh * 32 + 16 + lo) * 512 + g);
#pragma unroll
        for (int nf = 0; nf < 8; nf++) {
            short8 bfr = ld8(w1b + ((chh * 8 + nf) * 16 + lo) * DIM + t * 32 + hi * 8);
            f1a[nf] = mfma16(aA, bfr, f1a[nf]);
            f1b[nf] = mfma16(aB, bfr, f1b[nf]);
        }
    }
    u16* hl = (u16*)kls;   // [64][264]
#pragma unroll
    for (int nf = 0; nf < 8; nf++) {
        int f = (chh * 8 + nf) * 16 + lo;
        float bias = b1[f];
#pragma unroll
        for (int r = 0; r < 4; r++) {
            float va = f1a[nf][r] + bias;
            float vb2 = f1b[nf][r] + bias;
            float ga = 0.5f * va * (1.f + erff(va * 0.70710678f));
            float gb = 0.5f * vb2 * (1.f + erff(vb2 * 0.70710678f));
            hl[(rh * 32 + hi * 4 + r) * 264 + f]      = f2b(ga);
            hl[(rh * 32 + 16 + hi * 4 + r) * 264 + f] = f2b(gb);
        }
    }
    __syncthreads();

    f32x4 f2a[8], f2b_[8];
#pragma unroll
    for (int i = 0; i < 8; i++) {
        f2a[i] = (f32x4){0.f, 0.f, 0.f, 0.f};
        f2b_[i] = (f32x4){0.f, 0.f, 0.f, 0.f};
    }
#pragma unroll
    for (int t = 0; t < 8; t++) {
        short8 hA = ld8(hl + (rh * 32 + lo) * 264 + t * 32 + hi * 8);
        short8 hB = ld8(hl + (rh * 32 + 16 + lo) * 264 + t * 32 + hi * 8);
#pragma unroll
        for (int mf = 0; mf < 8; mf++) {
            short8 a2 = ld8(w2b + ((chh * 8 + mf) * 16 + lo) * DIM + t * 32 + hi * 8);
            f2a[mf] = mfma16(a2, hA, f2a[mf]);
            f2b_[mf] = mfma16(a2, hB, f2b_[mf]);
        }
    }
    int nA = qt * 64 + rh * 32 + lo;
    int nB = nA + 16;
#pragma unroll
    for (int mf = 0; mf < 8; mf++) {
#pragma unroll
        for (int r = 0; r < 4; r++) {
            int co = (chh * 8 + mf) * 16 + hi * 4 + r;
            size_t rowb = (size_t)b * (DIM * NTOK) + (size_t)co * NTOK;
            out[rowb + nA] = f2a[mf][r] + b2[co] + x[rowb + nA];
            out[rowb + nB] = f2b_[mf][r] + b2[co] + x[rowb + nB];
        }
    }
}

extern "C" void kernel_launch(void* const* d_in, const int* in_sizes, int n_in,
                              void* d_out, int out_size, void* d_ws, size_t ws_size,
                              hipStream_t stream) {
    const float* x      = (const float*)d_in[0];
    const float* proj_w = (const float*)d_in[1];
    const float* proj_b = (const float*)d_in[2];
    const float* w1     = (const float*)d_in[3];
    const float* b1     = (const float*)d_in[4];
    const float* w2     = (const float*)d_in[5];
    const float* b2     = (const float*)d_in[6];
    float* out = (float*)d_out;

    u16* xbf   = (u16*)d_ws;
    u16* nodes = xbf   + 4194304;
    u16* qb    = nodes + 4194304;
    u16* wbf   = qb    + 4194304;

    pack_kernel    <<<1120, 256, 0, stream>>>(x, xbf, nodes, proj_w, w1, w2, wbf);
    proj_kernel    <<<1024, 256, 0, stream>>>(nodes, wbf, proj_b, qb);
    attn_ffn_kernel<<<256,  256, 0, stream>>>(qb, xbf, wbf, b1, b2, x, out);
}